// Round 10
// baseline (864.465 us; speedup 1.0000x reference)
//
#include <hip/hip_runtime.h>
#include <hip/hip_fp16.h>
#include <math.h>

#define NN 100000
#define EE 3200000
#define D 128
#define NB 391        // coarse buckets: node>>8
#define NBLK2 1024    // blocks for hist/scatter passes
#define ECH2 (EE / NBLK2)   // 3125 edges per block (exact)
#define NSTRIP (NN / 32)
#define SL 3200000    // bytes per column-slice region = NN*32

#define SCALE_R 6.0f      // per-round rescale keeps fp8 values ~O(0.3)
#define SCALE_G 512.0f    // post-GEMM1 rescale
#define WSCALE  16.0f     // weight fp8 scale (avoid subnormals)
#define PRE1 (1.0f / (216.0f * WSCALE))            // undo h*6^3, W*16
#define PRE2 (1.0f / (216.0f * SCALE_G * WSCALE))  // undo h2*512*6^3, W*16

typedef float floatx16 __attribute__((ext_vector_type(16)));
typedef float v2f __attribute__((ext_vector_type(2)));

// ---------------- build pass 1: per-block histogram (transposed store) --------
__global__ __launch_bounds__(256) void block_hist(const int* __restrict__ dst,
                                                  int* __restrict__ bh) {
    __shared__ int hist[NB];
    for (int i = threadIdx.x; i < NB; i += 256) hist[i] = 0;
    __syncthreads();
    int e0 = blockIdx.x * ECH2;
    for (int e = e0 + threadIdx.x; e < e0 + ECH2; e += 256)
        atomicAdd(&hist[dst[e] >> 8], 1);
    __syncthreads();
    for (int i = threadIdx.x; i < NB; i += 256)
        bh[i * NBLK2 + blockIdx.x] = hist[i];
}

// ---------------- build pass 2: per-bin exclusive scan over blocks ------------
__global__ __launch_bounds__(256) void bin_scan(int* __restrict__ bh,
                                                int* __restrict__ bintot) {
    __shared__ int ts[256];
    int i = blockIdx.x;
    int t = threadIdx.x;
    int4 v = ((int4*)(bh + i * NBLK2))[t];
    int s = v.x + v.y + v.z + v.w;
    ts[t] = s;
    __syncthreads();
    for (int off = 1; off < 256; off <<= 1) {
        int x = (t >= off) ? ts[t - off] : 0;
        __syncthreads();
        ts[t] += x;
        __syncthreads();
    }
    int run = ts[t] - s;
    int4 o;
    o.x = run; o.y = run + v.x; o.z = o.y + v.y; o.w = o.z + v.z;
    ((int4*)(bh + i * NBLK2))[t] = o;
    if (t == 255) bintot[i] = ts[255];
}

// ---------------- build pass 3: exclusive scan of bin totals -> coff ----------
__global__ __launch_bounds__(512) void tiny_scan(const int* __restrict__ bintot,
                                                 int* __restrict__ coff) {
    __shared__ int s[512];
    int t = threadIdx.x;
    int v = (t < NB) ? bintot[t] : 0;
    s[t] = v;
    __syncthreads();
    for (int off = 1; off < 512; off <<= 1) {
        int x = (t >= off) ? s[t - off] : 0;
        __syncthreads();
        s[t] += x;
        __syncthreads();
    }
    int excl = s[t] - v;
    if (t <= NB) coff[t] = excl;   // coff[NB] == EE
}

// ---------------- build pass 4: scatter with precomputed bases ----------------
__global__ __launch_bounds__(256) void scatter2(const int* __restrict__ src,
                                                const int* __restrict__ dst,
                                                const int* __restrict__ bh,
                                                const int* __restrict__ coff,
                                                int2* __restrict__ ebuf) {
    __shared__ int base[NB];
    int b = blockIdx.x;
    for (int i = threadIdx.x; i < NB; i += 256)
        base[i] = coff[i] + bh[i * NBLK2 + b];
    __syncthreads();
    int e0 = b * ECH2;
    for (int e = e0 + threadIdx.x; e < e0 + ECH2; e += 256) {
        int d = dst[e];
        int pos = atomicAdd(&base[d >> 8], 1);
        ebuf[pos] = make_int2(src[e], d);
    }
}

// ---------------- build pass 5: per-bucket fine sort -> rowptr/norm/csr -------
// csr entries stored pre-shifted <<5 (byte offset into a 32B-slice region).
__global__ __launch_bounds__(256) void fine_sort(const long long* __restrict__ ebuf,
                                                 const int* __restrict__ coarse_off,
                                                 int* __restrict__ rowptr,
                                                 float* __restrict__ norm,
                                                 int* __restrict__ csr) {
    __shared__ int cnt[256];
    __shared__ int sbuf[256];
    int b = blockIdx.x;
    int t = threadIdx.x;
    int e0 = coarse_off[b], e1 = coarse_off[b + 1];
    int n0 = b << 8;
    cnt[t] = 0;
    __syncthreads();
    for (int e = e0 + t; e < e1; e += 256) {
        long long pv = ebuf[e];                 // normal load: prefetches for 2nd pass
        atomicAdd(&cnt[(int)(pv >> 32) & 255], 1);
    }
    __syncthreads();
    int myc = cnt[t];
    sbuf[t] = myc;
    __syncthreads();
    for (int off = 1; off < 256; off <<= 1) {
        int x = (t >= off) ? sbuf[t - off] : 0;
        __syncthreads();
        sbuf[t] += x;
        __syncthreads();
    }
    int excl = sbuf[t] - myc;
    int node = n0 + t;
    if (node < NN) {
        rowptr[node] = e0 + excl;
        float dd = (float)myc;
        if (dd < 1.0f) dd = 1.0f;
        norm[node] = rsqrtf(dd);
    }
    cnt[t] = e0 + excl;
    __syncthreads();
    for (int e = e0 + t; e < e1; e += 256) {
        long long pv = __builtin_nontemporal_load(ebuf + e);  // last use: stream
        int pos = atomicAdd(&cnt[(int)(pv >> 32) & 255], 1);
        csr[pos] = (int)pv << 5;                // pre-scaled byte offset
    }
    if (b == 0 && t == 0) rowptr[NN] = EE;
}

// ------- weight convert + transpose to fp8: Wt8[n*D+k] = fp8(W[k*D+n]*16) -----
__global__ void conv_w_fp8(const float* __restrict__ W, char* __restrict__ Wt8) {
    int idx = blockIdx.x * 256 + threadIdx.x;   // D*D/2 threads, 2 k each
    if (idx < D * D / 2) {
        int n = idx >> 6, k2 = (idx & 63) * 2;
        float a = W[k2 * D + n] * WSCALE;
        float b = W[(k2 + 1) * D + n] * WSCALE;
        int pk = __builtin_amdgcn_cvt_pk_fp8_f32(a, b, 0, 0);
        ((short*)Wt8)[idx] = (short)(pk & 0xffff);
    }
}

// ---------------- convert+scale: g0 = fp8(x * norm), slice-major layout -------
__global__ void convert_scale_fp8(const float4* __restrict__ x4, char* __restrict__ g,
                                  const float* __restrict__ norm) {
    int idx = blockIdx.x * 256 + threadIdx.x;   // NN*32 threads, 4 cols each
    if (idx < NN * 32) {
        int row = idx >> 5;
        int j = idx & 31;                       // 4-byte chunk within row
        float n = norm[row];
        float4 v = x4[idx];
        int w = __builtin_amdgcn_cvt_pk_fp8_f32(v.x * n, v.y * n, 0, 0);
        w = __builtin_amdgcn_cvt_pk_fp8_f32(v.z * n, v.w * n, w, 1);
        *(int*)(g + (size_t)(j >> 3) * SL + (unsigned)row * 32 + (j & 7) * 4) = w;
    }
}

// ---------------- XCD-sliced CSR gather on fp8 rows ----------------
// slice = blockIdx&3 (32 B of the row); with round-robin block->XCD dispatch,
// each XCD touches only one 3.2 MB slice -> L2-resident.
// Wave: 4 nodes x 8 edges x 2 chunks (lane = n*16 + e*2 + c).
template <int FINAL>
__global__ __launch_bounds__(256) void gather_fp8(const int* __restrict__ rowptr,
                                                  const int* __restrict__ csr,  // <<5
                                                  const char* __restrict__ hs,
                                                  const float* __restrict__ norm,
                                                  char* __restrict__ outv, float post) {
    int slice = blockIdx.x & 3;
    int wave = threadIdx.x >> 6;
    int lane = threadIdx.x & 63;
    int n = lane >> 4;
    int e = (lane >> 1) & 7;
    int c = lane & 1;
    int node = (blockIdx.x >> 2) * 16 + wave * 4 + n;
    int p0 = rowptr[node], p1 = rowptr[node + 1];
    const char* hsl = hs + (size_t)slice * SL + (c << 4);
    v2f acc[8];
#pragma unroll
    for (int i = 0; i < 8; ++i) acc[i] = (v2f)(0.0f);
    for (int p = p0 + e; p < p1; p += 8) {
        int soff = __builtin_nontemporal_load(csr + p);   // single-use per slice-pass
        int4 v = *(const int4*)(hsl + (unsigned)soff);
        acc[0] += __builtin_amdgcn_cvt_pk_f32_fp8(v.x, 0);
        acc[1] += __builtin_amdgcn_cvt_pk_f32_fp8(v.x, 1);
        acc[2] += __builtin_amdgcn_cvt_pk_f32_fp8(v.y, 0);
        acc[3] += __builtin_amdgcn_cvt_pk_f32_fp8(v.y, 1);
        acc[4] += __builtin_amdgcn_cvt_pk_f32_fp8(v.z, 0);
        acc[5] += __builtin_amdgcn_cvt_pk_f32_fp8(v.z, 1);
        acc[6] += __builtin_amdgcn_cvt_pk_f32_fp8(v.w, 0);
        acc[7] += __builtin_amdgcn_cvt_pk_f32_fp8(v.w, 1);
    }
#pragma unroll
    for (int off = 2; off <= 8; off <<= 1) {    // reduce over e (lane bits [3:1])
#pragma unroll
        for (int i = 0; i < 8; ++i) {
            acc[i].x += __shfl_xor(acc[i].x, off, 64);
            acc[i].y += __shfl_xor(acc[i].y, off, 64);
        }
    }
    if (e == 0) {
        float nr = norm[node];
        float m = (FINAL ? nr : nr * nr) * post;
        int4 w;
        w.x = __builtin_amdgcn_cvt_pk_fp8_f32(acc[0].x * m, acc[0].y * m, 0, 0);
        w.x = __builtin_amdgcn_cvt_pk_fp8_f32(acc[1].x * m, acc[1].y * m, w.x, 1);
        w.y = __builtin_amdgcn_cvt_pk_fp8_f32(acc[2].x * m, acc[2].y * m, 0, 0);
        w.y = __builtin_amdgcn_cvt_pk_fp8_f32(acc[3].x * m, acc[3].y * m, w.y, 1);
        w.z = __builtin_amdgcn_cvt_pk_fp8_f32(acc[4].x * m, acc[4].y * m, 0, 0);
        w.z = __builtin_amdgcn_cvt_pk_fp8_f32(acc[5].x * m, acc[5].y * m, w.z, 1);
        w.w = __builtin_amdgcn_cvt_pk_fp8_f32(acc[6].x * m, acc[6].y * m, 0, 0);
        w.w = __builtin_amdgcn_cvt_pk_fp8_f32(acc[7].x * m, acc[7].y * m, w.w, 1);
        *(int4*)(outv + (size_t)slice * SL + (unsigned)node * 32 + (c << 4)) = w;
    }
}

// ------- fp8 MFMA GEMM1 (sliced layout in/out) --------------------------------
__global__ __launch_bounds__(256) void gemm1_mfma(const char* __restrict__ H8,
                                                  const char* __restrict__ Wt8,
                                                  const float* __restrict__ b,
                                                  const float* __restrict__ norm,
                                                  char* __restrict__ out8) {
    int lane = threadIdx.x & 63;
    int w = threadIdx.x >> 6;
    int m = lane & 31;
    int q = lane >> 5;
    int col = w * 32 + m;
    long bf[8];
    const long* wp = (const long*)(Wt8 + (size_t)col * D + q * 8);
#pragma unroll
    for (int kc = 0; kc < 8; ++kc) bf[kc] = wp[kc * 2];
    float bc = b[col];
    char* outb = out8 + (size_t)(col >> 5) * SL + (col & 31);
    for (int s = blockIdx.x; s < NSTRIP; s += gridDim.x) {
        int r0 = s * 32;
        floatx16 acc;
#pragma unroll
        for (int i = 0; i < 16; ++i) acc[i] = 0.0f;
        const char* abase = H8 + (unsigned)(r0 + m) * 32 + q * 8;
#pragma unroll
        for (int kc = 0; kc < 8; ++kc) {
            long af = *(const long*)(abase + (size_t)(kc >> 1) * SL + (kc & 1) * 16);
            acc = __builtin_amdgcn_mfma_f32_32x32x16_fp8_fp8(af, bf[kc], acc, 0, 0, 0);
        }
#pragma unroll
        for (int r = 0; r < 16; ++r) {
            int row = r0 + (r & 3) + 8 * (r >> 2) + 4 * q;
            float v = fmaxf(acc[r] * PRE1 + bc, 0.0f) * norm[row] * SCALE_G;
            int pk = __builtin_amdgcn_cvt_pk_fp8_f32(v, v, 0, 0);
            outb[(unsigned)row * 32] = (char)(pk & 0xff);
        }
    }
}

// ------- fp8 MFMA GEMM2: colsum (sliced layout in) ----------------------------
__global__ __launch_bounds__(256) void gemm2_mfma_colsum(const char* __restrict__ H8,
                                                         const char* __restrict__ Wt8,
                                                         const float* __restrict__ b,
                                                         float* __restrict__ colsum) {
    int lane = threadIdx.x & 63;
    int w = threadIdx.x >> 6;
    int m = lane & 31;
    int q = lane >> 5;
    int col = w * 32 + m;
    long bf[8];
    const long* wp = (const long*)(Wt8 + (size_t)col * D + q * 8);
#pragma unroll
    for (int kc = 0; kc < 8; ++kc) bf[kc] = wp[kc * 2];
    float bc = b[col];
    float csum = 0.0f;
    for (int s = blockIdx.x; s < NSTRIP; s += gridDim.x) {
        int r0 = s * 32;
        floatx16 acc;
#pragma unroll
        for (int i = 0; i < 16; ++i) acc[i] = 0.0f;
        const char* abase = H8 + (unsigned)(r0 + m) * 32 + q * 8;
#pragma unroll
        for (int kc = 0; kc < 8; ++kc) {
            long af = *(const long*)(abase + (size_t)(kc >> 1) * SL + (kc & 1) * 16);
            acc = __builtin_amdgcn_mfma_f32_32x32x16_fp8_fp8(af, bf[kc], acc, 0, 0, 0);
        }
#pragma unroll
        for (int r = 0; r < 16; ++r) csum += fmaxf(acc[r] * PRE2 + bc, 0.0f);
    }
    csum += __shfl_down(csum, 32);
    if (lane < 32) atomicAdd(&colsum[col], csum);
}

// ---------------- final tiny MLP + sigmoid ----------------
__global__ __launch_bounds__(128) void final_mlp(const float* __restrict__ colsum,
                                                 const float* __restrict__ Wf1,
                                                 const float* __restrict__ bf1,
                                                 const float* __restrict__ Wf2,
                                                 const float* __restrict__ bf2,
                                                 float* __restrict__ out) {
    __shared__ float hg[D];
    __shared__ float red[D];
    int j = threadIdx.x;
    hg[j] = colsum[j] * (1.0f / (float)NN);
    __syncthreads();
    float acc = bf1[j];
#pragma unroll 16
    for (int k = 0; k < D; ++k)
        acc = fmaf(hg[k], Wf1[k * D + j], acc);
    acc = fmaxf(acc, 0.0f);
    red[j] = acc * Wf2[j];
    __syncthreads();
    for (int s = 64; s > 0; s >>= 1) {
        if (j < s) red[j] += red[j + s];
        __syncthreads();
    }
    if (j == 0) {
        float o = red[0] + bf2[0];
        o = fmaxf(o, 0.0f);
        out[0] = 1.0f / (1.0f + expf(-o));
    }
}

// ---------------- launch ------------------------------------------------------
extern "C" void kernel_launch(void* const* d_in, const int* in_sizes, int n_in,
                              void* d_out, int out_size, void* d_ws, size_t ws_size,
                              hipStream_t stream) {
    const float* x   = (const float*)d_in[0];
    const int*   src = (const int*)d_in[1];
    const int*   dst = (const int*)d_in[2];
    const float* W1  = (const float*)d_in[3];
    const float* b1  = (const float*)d_in[4];
    const float* W2  = (const float*)d_in[5];
    const float* b2  = (const float*)d_in[6];
    const float* Wf1 = (const float*)d_in[7];
    const float* bf1 = (const float*)d_in[8];
    const float* Wf2 = (const float*)d_in[9];
    const float* bf2 = (const float*)d_in[10];
    float* out = (float*)d_out;

    char* ws = (char*)d_ws;
    constexpr size_t OFF_BT   = 0;                              // NB ints
    constexpr size_t OFF_CO   = 2048;                           // NB+1 ints
    constexpr size_t OFF_CS   = 4096;                           // colsum
    constexpr size_t OFF_WT1  = 8192;                           // 16 KB fp8
    constexpr size_t OFF_WT2  = OFF_WT1 + 16384;
    constexpr size_t OFF_RP   = OFF_WT2 + 16384;                // NN+1 ints
    constexpr size_t OFF_NORM = OFF_RP + 400128;
    constexpr size_t OFF_BH   = OFF_NORM + 400128;              // NB*NBLK2 ints (1.6 MB)
    constexpr size_t OFF_EBUF = OFF_BH + (size_t)NB * NBLK2 * 4;// EE int2 (25.6 MB)
    constexpr size_t OFF_CSR  = OFF_EBUF + (size_t)EE * 8;      // EE ints (12.8 MB)
    constexpr size_t OFF_A8   = OFF_CSR + (size_t)EE * 4;       // 4*SL fp8 (12.8 MB)
    constexpr size_t OFF_B8   = OFF_A8 + (size_t)4 * SL;        // 4*SL fp8
    int*    bintot = (int*)(ws + OFF_BT);
    int*    coff   = (int*)(ws + OFF_CO);
    float*  colsum = (float*)(ws + OFF_CS);
    char*   Wt1    = ws + OFF_WT1;
    char*   Wt2    = ws + OFF_WT2;
    int*    rowptr = (int*)(ws + OFF_RP);
    float*  norm   = (float*)(ws + OFF_NORM);
    int*    bh     = (int*)(ws + OFF_BH);
    int2*   ebuf   = (int2*)(ws + OFF_EBUF);
    int*    csr    = (int*)(ws + OFF_CSR);
    char*   bufA8  = ws + OFF_A8;
    char*   bufB8  = ws + OFF_B8;

    const int nT = 256;
    const int gridC = (NN * 32 + nT - 1) / nT;
    const int gridG = (NN / 16) * 4;   // 25000 blocks: 16 nodes x 4 slices

    // ---- CSR build + norm (no global atomics) ----
    block_hist<<<NBLK2, 256, 0, stream>>>(dst, bh);
    bin_scan<<<NB, 256, 0, stream>>>(bh, bintot);
    tiny_scan<<<1, 512, 0, stream>>>(bintot, coff);
    scatter2<<<NBLK2, 256, 0, stream>>>(src, dst, bh, coff, ebuf);
    fine_sort<<<NB, 256, 0, stream>>>((const long long*)ebuf, coff, rowptr, norm, csr);

    // ---- weight prep (fp8, transposed, x16) ----
    conv_w_fp8<<<32, 256, 0, stream>>>(W1, Wt1);
    conv_w_fp8<<<32, 256, 0, stream>>>(W2, Wt2);

    // ---- propagation block 1 (fp8 sliced rows, cumulative x6 per round) ----
    convert_scale_fp8<<<gridC, nT, 0, stream>>>((const float4*)x, bufA8, norm);
    gather_fp8<0><<<gridG, 256, 0, stream>>>(rowptr, csr, bufA8, norm, bufB8, SCALE_R);
    gather_fp8<0><<<gridG, 256, 0, stream>>>(rowptr, csr, bufB8, norm, bufA8, SCALE_R);
    gather_fp8<1><<<gridG, 256, 0, stream>>>(rowptr, csr, bufA8, norm, bufB8, SCALE_R);
    // bufB8 = h * 216 (fp8, sliced)

    // ---- g = fp8(relu(h @ W1 + b1) * norm * SCALE_G) : B -> A (fp8 MFMA) ----
    gemm1_mfma<<<625, 256, 0, stream>>>(bufB8, Wt1, b1, norm, bufA8);

    // ---- propagation block 2 ----
    gather_fp8<0><<<gridG, 256, 0, stream>>>(rowptr, csr, bufA8, norm, bufB8, SCALE_R);
    gather_fp8<0><<<gridG, 256, 0, stream>>>(rowptr, csr, bufB8, norm, bufA8, SCALE_R);
    gather_fp8<1><<<gridG, 256, 0, stream>>>(rowptr, csr, bufA8, norm, bufB8, SCALE_R);
    // bufB8 = h2 * 512 * 216 (fp8, sliced)

    // ---- colsum of relu(h2 @ W2 + b2) (fp8 MFMA) ----
    hipMemsetAsync(colsum, 0, D * 4, stream);
    gemm2_mfma_colsum<<<250, 256, 0, stream>>>(bufB8, Wt2, b2, colsum);

    // ---- final MLP + sigmoid ----
    final_mlp<<<1, 128, 0, stream>>>(colsum, Wf1, bf1, Wf2, bf2, out);
}

// Round 11
// 715.743 us; speedup vs baseline: 1.2078x; 1.2078x over previous
//
#include <hip/hip_runtime.h>
#include <hip/hip_fp16.h>
#include <math.h>

#define NN 100000
#define EE 3200000
#define D 128
#define NB 391        // coarse buckets: node>>8
#define NBLK2 1024    // blocks for hist/scatter passes
#define ECH2 (EE / NBLK2)   // 3125 edges per block (exact)
#define NSTRIP (NN / 32)
#define SL 3200000    // bytes per column-slice region = NN*32

#define SCALE_R 6.0f      // per-round rescale keeps fp8 values ~O(0.3)
#define SCALE_G 512.0f    // post-GEMM1 rescale
#define WSCALE  16.0f     // weight fp8 scale (avoid subnormals)
#define PRE1 (1.0f / (216.0f * WSCALE))            // undo h*6^3, W*16
#define PRE2 (1.0f / (216.0f * SCALE_G * WSCALE))  // undo h2*512*6^3, W*16

typedef float floatx16 __attribute__((ext_vector_type(16)));
typedef float v2f __attribute__((ext_vector_type(2)));

// ---------------- build pass 1: per-block histogram (transposed store) --------
__global__ __launch_bounds__(256) void block_hist(const int* __restrict__ dst,
                                                  int* __restrict__ bh) {
    __shared__ int hist[NB];
    for (int i = threadIdx.x; i < NB; i += 256) hist[i] = 0;
    __syncthreads();
    int e0 = blockIdx.x * ECH2;
    for (int e = e0 + threadIdx.x; e < e0 + ECH2; e += 256)
        atomicAdd(&hist[dst[e] >> 8], 1);
    __syncthreads();
    for (int i = threadIdx.x; i < NB; i += 256)
        bh[i * NBLK2 + blockIdx.x] = hist[i];
}

// ---------------- build pass 2: per-bin exclusive scan over blocks ------------
__global__ __launch_bounds__(256) void bin_scan(int* __restrict__ bh,
                                                int* __restrict__ bintot) {
    __shared__ int ts[256];
    int i = blockIdx.x;
    int t = threadIdx.x;
    int4 v = ((int4*)(bh + i * NBLK2))[t];
    int s = v.x + v.y + v.z + v.w;
    ts[t] = s;
    __syncthreads();
    for (int off = 1; off < 256; off <<= 1) {
        int x = (t >= off) ? ts[t - off] : 0;
        __syncthreads();
        ts[t] += x;
        __syncthreads();
    }
    int run = ts[t] - s;
    int4 o;
    o.x = run; o.y = run + v.x; o.z = o.y + v.y; o.w = o.z + v.z;
    ((int4*)(bh + i * NBLK2))[t] = o;
    if (t == 255) bintot[i] = ts[255];
}

// ---------------- build pass 3: exclusive scan of bin totals -> coff ----------
__global__ __launch_bounds__(512) void tiny_scan(const int* __restrict__ bintot,
                                                 int* __restrict__ coff) {
    __shared__ int s[512];
    int t = threadIdx.x;
    int v = (t < NB) ? bintot[t] : 0;
    s[t] = v;
    __syncthreads();
    for (int off = 1; off < 512; off <<= 1) {
        int x = (t >= off) ? s[t - off] : 0;
        __syncthreads();
        s[t] += x;
        __syncthreads();
    }
    int excl = s[t] - v;
    if (t <= NB) coff[t] = excl;   // coff[NB] == EE
}

// ---------------- build pass 4: scatter with precomputed bases ----------------
__global__ __launch_bounds__(256) void scatter2(const int* __restrict__ src,
                                                const int* __restrict__ dst,
                                                const int* __restrict__ bh,
                                                const int* __restrict__ coff,
                                                int2* __restrict__ ebuf) {
    __shared__ int base[NB];
    int b = blockIdx.x;
    for (int i = threadIdx.x; i < NB; i += 256)
        base[i] = coff[i] + bh[i * NBLK2 + b];
    __syncthreads();
    int e0 = b * ECH2;
    for (int e = e0 + threadIdx.x; e < e0 + ECH2; e += 256) {
        int d = dst[e];
        int pos = atomicAdd(&base[d >> 8], 1);
        ebuf[pos] = make_int2(src[e], d);
    }
}

// ---------------- build pass 5: per-bucket fine sort -> rowptr/norm/csr -------
// csr entries stored pre-shifted <<5 (byte offset into a 32B-slice region).
__global__ __launch_bounds__(256) void fine_sort(const long long* __restrict__ ebuf,
                                                 const int* __restrict__ coarse_off,
                                                 int* __restrict__ rowptr,
                                                 float* __restrict__ norm,
                                                 int* __restrict__ csr) {
    __shared__ int cnt[256];
    __shared__ int sbuf[256];
    int b = blockIdx.x;
    int t = threadIdx.x;
    int e0 = coarse_off[b], e1 = coarse_off[b + 1];
    int n0 = b << 8;
    cnt[t] = 0;
    __syncthreads();
    for (int e = e0 + t; e < e1; e += 256) {
        long long pv = ebuf[e];                 // normal load: prefetches for 2nd pass
        atomicAdd(&cnt[(int)(pv >> 32) & 255], 1);
    }
    __syncthreads();
    int myc = cnt[t];
    sbuf[t] = myc;
    __syncthreads();
    for (int off = 1; off < 256; off <<= 1) {
        int x = (t >= off) ? sbuf[t - off] : 0;
        __syncthreads();
        sbuf[t] += x;
        __syncthreads();
    }
    int excl = sbuf[t] - myc;
    int node = n0 + t;
    if (node < NN) {
        rowptr[node] = e0 + excl;
        float dd = (float)myc;
        if (dd < 1.0f) dd = 1.0f;
        norm[node] = rsqrtf(dd);
    }
    cnt[t] = e0 + excl;
    __syncthreads();
    for (int e = e0 + t; e < e1; e += 256) {
        long long pv = __builtin_nontemporal_load(ebuf + e);  // last use: stream
        int pos = atomicAdd(&cnt[(int)(pv >> 32) & 255], 1);
        csr[pos] = (int)pv << 5;                // pre-scaled byte offset
    }
    if (b == 0 && t == 0) rowptr[NN] = EE;
}

// ------- weight convert + transpose to fp8: Wt8[n*D+k] = fp8(W[k*D+n]*16) -----
__global__ void conv_w_fp8(const float* __restrict__ W, char* __restrict__ Wt8) {
    int idx = blockIdx.x * 256 + threadIdx.x;   // D*D/2 threads, 2 k each
    if (idx < D * D / 2) {
        int n = idx >> 6, k2 = (idx & 63) * 2;
        float a = W[k2 * D + n] * WSCALE;
        float b = W[(k2 + 1) * D + n] * WSCALE;
        int pk = __builtin_amdgcn_cvt_pk_fp8_f32(a, b, 0, 0);
        ((short*)Wt8)[idx] = (short)(pk & 0xffff);
    }
}

// ---------------- convert+scale: g0 = fp8(x * norm), slice-major layout -------
__global__ void convert_scale_fp8(const float4* __restrict__ x4, char* __restrict__ g,
                                  const float* __restrict__ norm) {
    int idx = blockIdx.x * 256 + threadIdx.x;   // NN*32 threads, 4 cols each
    if (idx < NN * 32) {
        int row = idx >> 5;
        int j = idx & 31;                       // 4-byte chunk within row
        float n = norm[row];
        float4 v = x4[idx];
        int w = __builtin_amdgcn_cvt_pk_fp8_f32(v.x * n, v.y * n, 0, 0);
        w = __builtin_amdgcn_cvt_pk_fp8_f32(v.z * n, v.w * n, w, 1);
        *(int*)(g + (size_t)(j >> 3) * SL + (unsigned)row * 32 + (j & 7) * 4) = w;
    }
}

// ---------------- XCD-sliced CSR gather on fp8 rows ----------------
// slice = blockIdx&3 (32 B of the row); with round-robin block->XCD dispatch,
// each XCD touches only one 3.2 MB slice -> L2-resident.
// csr is a NORMAL cached load (R10's NT load forced 900-cyc HBM misses at the
// head of the dependent chain and defeated L3 retention across slice passes).
// Wave: 4 nodes x 8 edges x 2 chunks (lane = n*16 + e*2 + c).
template <int FINAL>
__global__ __launch_bounds__(256) void gather_fp8(const int* __restrict__ rowptr,
                                                  const int* __restrict__ csr,  // <<5
                                                  const char* __restrict__ hs,
                                                  const float* __restrict__ norm,
                                                  char* __restrict__ outv, float post) {
    int slice = blockIdx.x & 3;
    int wave = threadIdx.x >> 6;
    int lane = threadIdx.x & 63;
    int n = lane >> 4;
    int e = (lane >> 1) & 7;
    int c = lane & 1;
    int node = (blockIdx.x >> 2) * 16 + wave * 4 + n;
    int p0 = rowptr[node], p1 = rowptr[node + 1];
    const char* hsl = hs + (size_t)slice * SL + (c << 4);
    v2f acc[8];
#pragma unroll
    for (int i = 0; i < 8; ++i) acc[i] = (v2f)(0.0f);
    for (int p = p0 + e; p < p1; p += 8) {
        int soff = csr[p];                      // cached: L3-resident after round 1
        int4 v = *(const int4*)(hsl + (unsigned)soff);
        acc[0] += __builtin_amdgcn_cvt_pk_f32_fp8(v.x, 0);
        acc[1] += __builtin_amdgcn_cvt_pk_f32_fp8(v.x, 1);
        acc[2] += __builtin_amdgcn_cvt_pk_f32_fp8(v.y, 0);
        acc[3] += __builtin_amdgcn_cvt_pk_f32_fp8(v.y, 1);
        acc[4] += __builtin_amdgcn_cvt_pk_f32_fp8(v.z, 0);
        acc[5] += __builtin_amdgcn_cvt_pk_f32_fp8(v.z, 1);
        acc[6] += __builtin_amdgcn_cvt_pk_f32_fp8(v.w, 0);
        acc[7] += __builtin_amdgcn_cvt_pk_f32_fp8(v.w, 1);
    }
#pragma unroll
    for (int off = 2; off <= 8; off <<= 1) {    // reduce over e (lane bits [3:1])
#pragma unroll
        for (int i = 0; i < 8; ++i) {
            acc[i].x += __shfl_xor(acc[i].x, off, 64);
            acc[i].y += __shfl_xor(acc[i].y, off, 64);
        }
    }
    if (e == 0) {
        float nr = norm[node];
        float m = (FINAL ? nr : nr * nr) * post;
        int4 w;
        w.x = __builtin_amdgcn_cvt_pk_fp8_f32(acc[0].x * m, acc[0].y * m, 0, 0);
        w.x = __builtin_amdgcn_cvt_pk_fp8_f32(acc[1].x * m, acc[1].y * m, w.x, 1);
        w.y = __builtin_amdgcn_cvt_pk_fp8_f32(acc[2].x * m, acc[2].y * m, 0, 0);
        w.y = __builtin_amdgcn_cvt_pk_fp8_f32(acc[3].x * m, acc[3].y * m, w.y, 1);
        w.z = __builtin_amdgcn_cvt_pk_fp8_f32(acc[4].x * m, acc[4].y * m, 0, 0);
        w.z = __builtin_amdgcn_cvt_pk_fp8_f32(acc[5].x * m, acc[5].y * m, w.z, 1);
        w.w = __builtin_amdgcn_cvt_pk_fp8_f32(acc[6].x * m, acc[6].y * m, 0, 0);
        w.w = __builtin_amdgcn_cvt_pk_fp8_f32(acc[7].x * m, acc[7].y * m, w.w, 1);
        *(int4*)(outv + (size_t)slice * SL + (unsigned)node * 32 + (c << 4)) = w;
    }
}

// ------- fp8 MFMA GEMM1 (sliced layout in/out) --------------------------------
__global__ __launch_bounds__(256) void gemm1_mfma(const char* __restrict__ H8,
                                                  const char* __restrict__ Wt8,
                                                  const float* __restrict__ b,
                                                  const float* __restrict__ norm,
                                                  char* __restrict__ out8) {
    int lane = threadIdx.x & 63;
    int w = threadIdx.x >> 6;
    int m = lane & 31;
    int q = lane >> 5;
    int col = w * 32 + m;
    long bf[8];
    const long* wp = (const long*)(Wt8 + (size_t)col * D + q * 8);
#pragma unroll
    for (int kc = 0; kc < 8; ++kc) bf[kc] = wp[kc * 2];
    float bc = b[col];
    char* outb = out8 + (size_t)(col >> 5) * SL + (col & 31);
    for (int s = blockIdx.x; s < NSTRIP; s += gridDim.x) {
        int r0 = s * 32;
        floatx16 acc;
#pragma unroll
        for (int i = 0; i < 16; ++i) acc[i] = 0.0f;
        const char* abase = H8 + (unsigned)(r0 + m) * 32 + q * 8;
#pragma unroll
        for (int kc = 0; kc < 8; ++kc) {
            long af = *(const long*)(abase + (size_t)(kc >> 1) * SL + (kc & 1) * 16);
            acc = __builtin_amdgcn_mfma_f32_32x32x16_fp8_fp8(af, bf[kc], acc, 0, 0, 0);
        }
#pragma unroll
        for (int r = 0; r < 16; ++r) {
            int row = r0 + (r & 3) + 8 * (r >> 2) + 4 * q;
            float v = fmaxf(acc[r] * PRE1 + bc, 0.0f) * norm[row] * SCALE_G;
            int pk = __builtin_amdgcn_cvt_pk_fp8_f32(v, v, 0, 0);
            outb[(unsigned)row * 32] = (char)(pk & 0xff);
        }
    }
}

// ------- fp8 MFMA GEMM2: colsum (sliced layout in) ----------------------------
__global__ __launch_bounds__(256) void gemm2_mfma_colsum(const char* __restrict__ H8,
                                                         const char* __restrict__ Wt8,
                                                         const float* __restrict__ b,
                                                         float* __restrict__ colsum) {
    int lane = threadIdx.x & 63;
    int w = threadIdx.x >> 6;
    int m = lane & 31;
    int q = lane >> 5;
    int col = w * 32 + m;
    long bf[8];
    const long* wp = (const long*)(Wt8 + (size_t)col * D + q * 8);
#pragma unroll
    for (int kc = 0; kc < 8; ++kc) bf[kc] = wp[kc * 2];
    float bc = b[col];
    float csum = 0.0f;
    for (int s = blockIdx.x; s < NSTRIP; s += gridDim.x) {
        int r0 = s * 32;
        floatx16 acc;
#pragma unroll
        for (int i = 0; i < 16; ++i) acc[i] = 0.0f;
        const char* abase = H8 + (unsigned)(r0 + m) * 32 + q * 8;
#pragma unroll
        for (int kc = 0; kc < 8; ++kc) {
            long af = *(const long*)(abase + (size_t)(kc >> 1) * SL + (kc & 1) * 16);
            acc = __builtin_amdgcn_mfma_f32_32x32x16_fp8_fp8(af, bf[kc], acc, 0, 0, 0);
        }
#pragma unroll
        for (int r = 0; r < 16; ++r) csum += fmaxf(acc[r] * PRE2 + bc, 0.0f);
    }
    csum += __shfl_down(csum, 32);
    if (lane < 32) atomicAdd(&colsum[col], csum);
}

// ---------------- final tiny MLP + sigmoid ----------------
__global__ __launch_bounds__(128) void final_mlp(const float* __restrict__ colsum,
                                                 const float* __restrict__ Wf1,
                                                 const float* __restrict__ bf1,
                                                 const float* __restrict__ Wf2,
                                                 const float* __restrict__ bf2,
                                                 float* __restrict__ out) {
    __shared__ float hg[D];
    __shared__ float red[D];
    int j = threadIdx.x;
    hg[j] = colsum[j] * (1.0f / (float)NN);
    __syncthreads();
    float acc = bf1[j];
#pragma unroll 16
    for (int k = 0; k < D; ++k)
        acc = fmaf(hg[k], Wf1[k * D + j], acc);
    acc = fmaxf(acc, 0.0f);
    red[j] = acc * Wf2[j];
    __syncthreads();
    for (int s = 64; s > 0; s >>= 1) {
        if (j < s) red[j] += red[j + s];
        __syncthreads();
    }
    if (j == 0) {
        float o = red[0] + bf2[0];
        o = fmaxf(o, 0.0f);
        out[0] = 1.0f / (1.0f + expf(-o));
    }
}

// ---------------- launch ------------------------------------------------------
extern "C" void kernel_launch(void* const* d_in, const int* in_sizes, int n_in,
                              void* d_out, int out_size, void* d_ws, size_t ws_size,
                              hipStream_t stream) {
    const float* x   = (const float*)d_in[0];
    const int*   src = (const int*)d_in[1];
    const int*   dst = (const int*)d_in[2];
    const float* W1  = (const float*)d_in[3];
    const float* b1  = (const float*)d_in[4];
    const float* W2  = (const float*)d_in[5];
    const float* b2  = (const float*)d_in[6];
    const float* Wf1 = (const float*)d_in[7];
    const float* bf1 = (const float*)d_in[8];
    const float* Wf2 = (const float*)d_in[9];
    const float* bf2 = (const float*)d_in[10];
    float* out = (float*)d_out;

    char* ws = (char*)d_ws;
    constexpr size_t OFF_BT   = 0;                              // NB ints
    constexpr size_t OFF_CO   = 2048;                           // NB+1 ints
    constexpr size_t OFF_CS   = 4096;                           // colsum
    constexpr size_t OFF_WT1  = 8192;                           // 16 KB fp8
    constexpr size_t OFF_WT2  = OFF_WT1 + 16384;
    constexpr size_t OFF_RP   = OFF_WT2 + 16384;                // NN+1 ints
    constexpr size_t OFF_NORM = OFF_RP + 400128;
    constexpr size_t OFF_BH   = OFF_NORM + 400128;              // NB*NBLK2 ints (1.6 MB)
    constexpr size_t OFF_EBUF = OFF_BH + (size_t)NB * NBLK2 * 4;// EE int2 (25.6 MB)
    constexpr size_t OFF_CSR  = OFF_EBUF + (size_t)EE * 8;      // EE ints (12.8 MB)
    constexpr size_t OFF_A8   = OFF_CSR + (size_t)EE * 4;       // 4*SL fp8 (12.8 MB)
    constexpr size_t OFF_B8   = OFF_A8 + (size_t)4 * SL;        // 4*SL fp8
    int*    bintot = (int*)(ws + OFF_BT);
    int*    coff   = (int*)(ws + OFF_CO);
    float*  colsum = (float*)(ws + OFF_CS);
    char*   Wt1    = ws + OFF_WT1;
    char*   Wt2    = ws + OFF_WT2;
    int*    rowptr = (int*)(ws + OFF_RP);
    float*  norm   = (float*)(ws + OFF_NORM);
    int*    bh     = (int*)(ws + OFF_BH);
    int2*   ebuf   = (int2*)(ws + OFF_EBUF);
    int*    csr    = (int*)(ws + OFF_CSR);
    char*   bufA8  = ws + OFF_A8;
    char*   bufB8  = ws + OFF_B8;

    const int nT = 256;
    const int gridC = (NN * 32 + nT - 1) / nT;
    const int gridG = (NN / 16) * 4;   // 25000 blocks: 16 nodes x 4 slices

    // ---- CSR build + norm (no global atomics) ----
    block_hist<<<NBLK2, 256, 0, stream>>>(dst, bh);
    bin_scan<<<NB, 256, 0, stream>>>(bh, bintot);
    tiny_scan<<<1, 512, 0, stream>>>(bintot, coff);
    scatter2<<<NBLK2, 256, 0, stream>>>(src, dst, bh, coff, ebuf);
    fine_sort<<<NB, 256, 0, stream>>>((const long long*)ebuf, coff, rowptr, norm, csr);

    // ---- weight prep (fp8, transposed, x16) ----
    conv_w_fp8<<<32, 256, 0, stream>>>(W1, Wt1);
    conv_w_fp8<<<32, 256, 0, stream>>>(W2, Wt2);

    // ---- propagation block 1 (fp8 sliced rows, cumulative x6 per round) ----
    convert_scale_fp8<<<gridC, nT, 0, stream>>>((const float4*)x, bufA8, norm);
    gather_fp8<0><<<gridG, 256, 0, stream>>>(rowptr, csr, bufA8, norm, bufB8, SCALE_R);
    gather_fp8<0><<<gridG, 256, 0, stream>>>(rowptr, csr, bufB8, norm, bufA8, SCALE_R);
    gather_fp8<1><<<gridG, 256, 0, stream>>>(rowptr, csr, bufA8, norm, bufB8, SCALE_R);
    // bufB8 = h * 216 (fp8, sliced)

    // ---- g = fp8(relu(h @ W1 + b1) * norm * SCALE_G) : B -> A (fp8 MFMA) ----
    gemm1_mfma<<<625, 256, 0, stream>>>(bufB8, Wt1, b1, norm, bufA8);

    // ---- propagation block 2 ----
    gather_fp8<0><<<gridG, 256, 0, stream>>>(rowptr, csr, bufA8, norm, bufB8, SCALE_R);
    gather_fp8<0><<<gridG, 256, 0, stream>>>(rowptr, csr, bufB8, norm, bufA8, SCALE_R);
    gather_fp8<1><<<gridG, 256, 0, stream>>>(rowptr, csr, bufA8, norm, bufB8, SCALE_R);
    // bufB8 = h2 * 512 * 216 (fp8, sliced)

    // ---- colsum of relu(h2 @ W2 + b2) (fp8 MFMA) ----
    hipMemsetAsync(colsum, 0, D * 4, stream);
    gemm2_mfma_colsum<<<250, 256, 0, stream>>>(bufB8, Wt2, b2, colsum);

    // ---- final MLP + sigmoid ----
    final_mlp<<<1, 128, 0, stream>>>(colsum, Wf1, bf1, Wf2, bf2, out);
}

// Round 12
// 626.319 us; speedup vs baseline: 1.3802x; 1.1428x over previous
//
#include <hip/hip_runtime.h>
#include <hip/hip_fp16.h>
#include <math.h>

#define NN 100000
#define EE 3200000
#define D 128
#define NB 391        // coarse buckets: node>>8
#define NBLK2 1024    // blocks for hist/scatter passes
#define ECH2 (EE / NBLK2)   // 3125 edges per block (exact)
#define NSTRIP (NN / 32)

#define SCALE_R 6.0f      // per-round rescale keeps fp8 values ~O(0.3)
#define SCALE_G 512.0f    // post-GEMM1 rescale
#define WSCALE  16.0f     // weight fp8 scale (avoid subnormals)
#define PRE1 (1.0f / (216.0f * WSCALE))            // undo h*6^3, W*16
#define PRE2 (1.0f / (216.0f * SCALE_G * WSCALE))  // undo h2*512*6^3, W*16

typedef float floatx16 __attribute__((ext_vector_type(16)));
typedef float v2f __attribute__((ext_vector_type(2)));

// ---------------- build pass 1: per-block histogram (transposed store) --------
__global__ __launch_bounds__(256) void block_hist(const int* __restrict__ dst,
                                                  int* __restrict__ bh) {
    __shared__ int hist[NB];
    for (int i = threadIdx.x; i < NB; i += 256) hist[i] = 0;
    __syncthreads();
    int e0 = blockIdx.x * ECH2;
    for (int e = e0 + threadIdx.x; e < e0 + ECH2; e += 256)
        atomicAdd(&hist[dst[e] >> 8], 1);
    __syncthreads();
    for (int i = threadIdx.x; i < NB; i += 256)
        bh[i * NBLK2 + blockIdx.x] = hist[i];
}

// ---------------- build pass 2: per-bin exclusive scan over blocks ------------
__global__ __launch_bounds__(256) void bin_scan(int* __restrict__ bh,
                                                int* __restrict__ bintot) {
    __shared__ int ts[256];
    int i = blockIdx.x;
    int t = threadIdx.x;
    int4 v = ((int4*)(bh + i * NBLK2))[t];
    int s = v.x + v.y + v.z + v.w;
    ts[t] = s;
    __syncthreads();
    for (int off = 1; off < 256; off <<= 1) {
        int x = (t >= off) ? ts[t - off] : 0;
        __syncthreads();
        ts[t] += x;
        __syncthreads();
    }
    int run = ts[t] - s;
    int4 o;
    o.x = run; o.y = run + v.x; o.z = o.y + v.y; o.w = o.z + v.z;
    ((int4*)(bh + i * NBLK2))[t] = o;
    if (t == 255) bintot[i] = ts[255];
}

// ---------------- build pass 3: exclusive scan of bin totals -> coff ----------
__global__ __launch_bounds__(512) void tiny_scan(const int* __restrict__ bintot,
                                                 int* __restrict__ coff) {
    __shared__ int s[512];
    int t = threadIdx.x;
    int v = (t < NB) ? bintot[t] : 0;
    s[t] = v;
    __syncthreads();
    for (int off = 1; off < 512; off <<= 1) {
        int x = (t >= off) ? s[t - off] : 0;
        __syncthreads();
        s[t] += x;
        __syncthreads();
    }
    int excl = s[t] - v;
    if (t <= NB) coff[t] = excl;   // coff[NB] == EE
}

// ---------------- build pass 4: scatter with precomputed bases ----------------
__global__ __launch_bounds__(256) void scatter2(const int* __restrict__ src,
                                                const int* __restrict__ dst,
                                                const int* __restrict__ bh,
                                                const int* __restrict__ coff,
                                                int2* __restrict__ ebuf) {
    __shared__ int base[NB];
    int b = blockIdx.x;
    for (int i = threadIdx.x; i < NB; i += 256)
        base[i] = coff[i] + bh[i * NBLK2 + b];
    __syncthreads();
    int e0 = b * ECH2;
    for (int e = e0 + threadIdx.x; e < e0 + ECH2; e += 256) {
        int d = dst[e];
        int pos = atomicAdd(&base[d >> 8], 1);
        ebuf[pos] = make_int2(src[e], d);
    }
}

// ---------------- build pass 5: per-bucket fine sort -> rowptr/norm/csr -------
// csr entries stored pre-shifted <<7 (byte offset of the 128 B fp8 row).
__global__ __launch_bounds__(256) void fine_sort(const long long* __restrict__ ebuf,
                                                 const int* __restrict__ coarse_off,
                                                 int* __restrict__ rowptr,
                                                 float* __restrict__ norm,
                                                 int* __restrict__ csr) {
    __shared__ int cnt[256];
    __shared__ int sbuf[256];
    int b = blockIdx.x;
    int t = threadIdx.x;
    int e0 = coarse_off[b], e1 = coarse_off[b + 1];
    int n0 = b << 8;
    cnt[t] = 0;
    __syncthreads();
    for (int e = e0 + t; e < e1; e += 256) {
        long long pv = ebuf[e];                 // normal load: prefetches for 2nd pass
        atomicAdd(&cnt[(int)(pv >> 32) & 255], 1);
    }
    __syncthreads();
    int myc = cnt[t];
    sbuf[t] = myc;
    __syncthreads();
    for (int off = 1; off < 256; off <<= 1) {
        int x = (t >= off) ? sbuf[t - off] : 0;
        __syncthreads();
        sbuf[t] += x;
        __syncthreads();
    }
    int excl = sbuf[t] - myc;
    int node = n0 + t;
    if (node < NN) {
        rowptr[node] = e0 + excl;
        float dd = (float)myc;
        if (dd < 1.0f) dd = 1.0f;
        norm[node] = rsqrtf(dd);
    }
    cnt[t] = e0 + excl;
    __syncthreads();
    for (int e = e0 + t; e < e1; e += 256) {
        long long pv = __builtin_nontemporal_load(ebuf + e);  // last use: stream
        int pos = atomicAdd(&cnt[(int)(pv >> 32) & 255], 1);
        csr[pos] = (int)pv << 7;                // pre-scaled row byte offset
    }
    if (b == 0 && t == 0) rowptr[NN] = EE;
}

// ------- weight convert + transpose to fp8: Wt8[n*D+k] = fp8(W[k*D+n]*16) -----
__global__ void conv_w_fp8(const float* __restrict__ W, char* __restrict__ Wt8) {
    int idx = blockIdx.x * 256 + threadIdx.x;   // D*D/2 threads, 2 k each
    if (idx < D * D / 2) {
        int n = idx >> 6, k2 = (idx & 63) * 2;
        float a = W[k2 * D + n] * WSCALE;
        float b = W[(k2 + 1) * D + n] * WSCALE;
        int pk = __builtin_amdgcn_cvt_pk_fp8_f32(a, b, 0, 0);
        ((short*)Wt8)[idx] = (short)(pk & 0xffff);
    }
}

// ---------------- convert+scale: g0 = fp8(x * norm) ----------------
__global__ void convert_scale_fp8(const float4* __restrict__ x4, int* __restrict__ g,
                                  const float* __restrict__ norm) {
    int idx = blockIdx.x * 256 + threadIdx.x;   // NN*32 threads, 4 cols each
    if (idx < NN * 32) {
        int row = idx >> 5;
        float n = norm[row];
        float4 v = x4[idx];
        int w = __builtin_amdgcn_cvt_pk_fp8_f32(v.x * n, v.y * n, 0, 0);
        w = __builtin_amdgcn_cvt_pk_fp8_f32(v.z * n, v.w * n, w, 1);
        g[idx] = w;
    }
}

// ---------------- CSR gather on fp8 rows, 2-deep MLP ----------------
// One wave per node. lane = e*8 + c: 8 parallel edges x 8 col-chunks (16 fp8).
// Edge loop unrolled x2 with INDEPENDENT load pairs: two csr loads then two
// row loads issue back-to-back, doubling outstanding misses per lane
// (R9/R11 analysis: gather is latency*concurrency bound at ~2.1 TB/s fill;
// 2 chains/lane lifts the ceiling to ~4 TB/s > 3.3 TB/s fabric).
template <int FINAL>
__global__ __launch_bounds__(256) void gather_fp8(const int* __restrict__ rowptr,
                                                  const int* __restrict__ csr,  // <<7
                                                  const char* __restrict__ hs,
                                                  const float* __restrict__ norm,
                                                  char* __restrict__ outv, float post) {
    int node = blockIdx.x * 4 + (threadIdx.x >> 6);
    int lane = threadIdx.x & 63;
    int e = lane >> 3;
    int c = lane & 7;
    int p0 = rowptr[node], p1 = rowptr[node + 1];
    v2f acc[8];
#pragma unroll
    for (int i = 0; i < 8; ++i) acc[i] = (v2f)(0.0f);
    int coff16 = c << 4;
    int p = p0 + e;
#define CVT_ACC(v) { \
        acc[0] += __builtin_amdgcn_cvt_pk_f32_fp8((v).x, 0); \
        acc[1] += __builtin_amdgcn_cvt_pk_f32_fp8((v).x, 1); \
        acc[2] += __builtin_amdgcn_cvt_pk_f32_fp8((v).y, 0); \
        acc[3] += __builtin_amdgcn_cvt_pk_f32_fp8((v).y, 1); \
        acc[4] += __builtin_amdgcn_cvt_pk_f32_fp8((v).z, 0); \
        acc[5] += __builtin_amdgcn_cvt_pk_f32_fp8((v).z, 1); \
        acc[6] += __builtin_amdgcn_cvt_pk_f32_fp8((v).w, 0); \
        acc[7] += __builtin_amdgcn_cvt_pk_f32_fp8((v).w, 1); }
    for (; p + 8 < p1; p += 16) {
        int s0 = csr[p];
        int s1 = csr[p + 8];
        int4 v0 = *(const int4*)(hs + (unsigned)s0 + coff16);
        int4 v1 = *(const int4*)(hs + (unsigned)s1 + coff16);
        CVT_ACC(v0);
        CVT_ACC(v1);
    }
    if (p < p1) {
        int s0 = csr[p];
        int4 v0 = *(const int4*)(hs + (unsigned)s0 + coff16);
        CVT_ACC(v0);
    }
#undef CVT_ACC
#pragma unroll
    for (int off = 8; off < 64; off <<= 1) {
#pragma unroll
        for (int i = 0; i < 8; ++i) {
            acc[i].x += __shfl_xor(acc[i].x, off, 64);
            acc[i].y += __shfl_xor(acc[i].y, off, 64);
        }
    }
    if (e == 0) {
        float n = norm[node];
        float m = (FINAL ? n : n * n) * post;
        int4 w;
        w.x = __builtin_amdgcn_cvt_pk_fp8_f32(acc[0].x * m, acc[0].y * m, 0, 0);
        w.x = __builtin_amdgcn_cvt_pk_fp8_f32(acc[1].x * m, acc[1].y * m, w.x, 1);
        w.y = __builtin_amdgcn_cvt_pk_fp8_f32(acc[2].x * m, acc[2].y * m, 0, 0);
        w.y = __builtin_amdgcn_cvt_pk_fp8_f32(acc[3].x * m, acc[3].y * m, w.y, 1);
        w.z = __builtin_amdgcn_cvt_pk_fp8_f32(acc[4].x * m, acc[4].y * m, 0, 0);
        w.z = __builtin_amdgcn_cvt_pk_fp8_f32(acc[5].x * m, acc[5].y * m, w.z, 1);
        w.w = __builtin_amdgcn_cvt_pk_fp8_f32(acc[6].x * m, acc[6].y * m, 0, 0);
        w.w = __builtin_amdgcn_cvt_pk_fp8_f32(acc[7].x * m, acc[7].y * m, w.w, 1);
        *(int4*)(outv + (unsigned)node * 128 + coff16) = w;
    }
}

// ------- fp8 MFMA GEMM1: out_fp8 = fp8(relu(acc*PRE1 + b1) * norm * SCALE_G) --
__global__ __launch_bounds__(256) void gemm1_mfma(const char* __restrict__ H8,
                                                  const char* __restrict__ Wt8,
                                                  const float* __restrict__ b,
                                                  const float* __restrict__ norm,
                                                  char* __restrict__ out8) {
    int lane = threadIdx.x & 63;
    int w = threadIdx.x >> 6;
    int m = lane & 31;
    int q = lane >> 5;
    int col = w * 32 + m;
    long bf[8];
    const long* wp = (const long*)(Wt8 + (size_t)col * D + q * 8);
#pragma unroll
    for (int kc = 0; kc < 8; ++kc) bf[kc] = wp[kc * 2];
    float bc = b[col];
    for (int s = blockIdx.x; s < NSTRIP; s += gridDim.x) {
        int r0 = s * 32;
        floatx16 acc;
#pragma unroll
        for (int i = 0; i < 16; ++i) acc[i] = 0.0f;
        const long* ap = (const long*)(H8 + (size_t)(r0 + m) * D + q * 8);
#pragma unroll
        for (int kc = 0; kc < 8; ++kc)
            acc = __builtin_amdgcn_mfma_f32_32x32x16_fp8_fp8(ap[kc * 2], bf[kc], acc, 0, 0, 0);
#pragma unroll
        for (int r = 0; r < 16; ++r) {
            int row = r0 + (r & 3) + 8 * (r >> 2) + 4 * q;
            float v = fmaxf(acc[r] * PRE1 + bc, 0.0f) * norm[row] * SCALE_G;
            int pk = __builtin_amdgcn_cvt_pk_fp8_f32(v, v, 0, 0);
            out8[(size_t)row * D + col] = (char)(pk & 0xff);
        }
    }
}

// ------- fp8 MFMA GEMM2: colsum_j = sum_i relu(acc*PRE2 + b2)_ij --------------
__global__ __launch_bounds__(256) void gemm2_mfma_colsum(const char* __restrict__ H8,
                                                         const char* __restrict__ Wt8,
                                                         const float* __restrict__ b,
                                                         float* __restrict__ colsum) {
    int lane = threadIdx.x & 63;
    int w = threadIdx.x >> 6;
    int m = lane & 31;
    int q = lane >> 5;
    int col = w * 32 + m;
    long bf[8];
    const long* wp = (const long*)(Wt8 + (size_t)col * D + q * 8);
#pragma unroll
    for (int kc = 0; kc < 8; ++kc) bf[kc] = wp[kc * 2];
    float bc = b[col];
    float csum = 0.0f;
    for (int s = blockIdx.x; s < NSTRIP; s += gridDim.x) {
        int r0 = s * 32;
        floatx16 acc;
#pragma unroll
        for (int i = 0; i < 16; ++i) acc[i] = 0.0f;
        const long* ap = (const long*)(H8 + (size_t)(r0 + m) * D + q * 8);
#pragma unroll
        for (int kc = 0; kc < 8; ++kc)
            acc = __builtin_amdgcn_mfma_f32_32x32x16_fp8_fp8(ap[kc * 2], bf[kc], acc, 0, 0, 0);
#pragma unroll
        for (int r = 0; r < 16; ++r) csum += fmaxf(acc[r] * PRE2 + bc, 0.0f);
    }
    csum += __shfl_down(csum, 32);
    if (lane < 32) atomicAdd(&colsum[col], csum);
}

// ---------------- final tiny MLP + sigmoid ----------------
__global__ __launch_bounds__(128) void final_mlp(const float* __restrict__ colsum,
                                                 const float* __restrict__ Wf1,
                                                 const float* __restrict__ bf1,
                                                 const float* __restrict__ Wf2,
                                                 const float* __restrict__ bf2,
                                                 float* __restrict__ out) {
    __shared__ float hg[D];
    __shared__ float red[D];
    int j = threadIdx.x;
    hg[j] = colsum[j] * (1.0f / (float)NN);
    __syncthreads();
    float acc = bf1[j];
#pragma unroll 16
    for (int k = 0; k < D; ++k)
        acc = fmaf(hg[k], Wf1[k * D + j], acc);
    acc = fmaxf(acc, 0.0f);
    red[j] = acc * Wf2[j];
    __syncthreads();
    for (int s = 64; s > 0; s >>= 1) {
        if (j < s) red[j] += red[j + s];
        __syncthreads();
    }
    if (j == 0) {
        float o = red[0] + bf2[0];
        o = fmaxf(o, 0.0f);
        out[0] = 1.0f / (1.0f + expf(-o));
    }
}

// ---------------- launch ------------------------------------------------------
extern "C" void kernel_launch(void* const* d_in, const int* in_sizes, int n_in,
                              void* d_out, int out_size, void* d_ws, size_t ws_size,
                              hipStream_t stream) {
    const float* x   = (const float*)d_in[0];
    const int*   src = (const int*)d_in[1];
    const int*   dst = (const int*)d_in[2];
    const float* W1  = (const float*)d_in[3];
    const float* b1  = (const float*)d_in[4];
    const float* W2  = (const float*)d_in[5];
    const float* b2  = (const float*)d_in[6];
    const float* Wf1 = (const float*)d_in[7];
    const float* bf1 = (const float*)d_in[8];
    const float* Wf2 = (const float*)d_in[9];
    const float* bf2 = (const float*)d_in[10];
    float* out = (float*)d_out;

    char* ws = (char*)d_ws;
    constexpr size_t OFF_BT   = 0;                              // NB ints
    constexpr size_t OFF_CO   = 2048;                           // NB+1 ints
    constexpr size_t OFF_CS   = 4096;                           // colsum
    constexpr size_t OFF_WT1  = 8192;                           // 16 KB fp8
    constexpr size_t OFF_WT2  = OFF_WT1 + 16384;
    constexpr size_t OFF_RP   = OFF_WT2 + 16384;                // NN+1 ints
    constexpr size_t OFF_NORM = OFF_RP + 400128;
    constexpr size_t OFF_BH   = OFF_NORM + 400128;              // NB*NBLK2 ints (1.6 MB)
    constexpr size_t OFF_EBUF = OFF_BH + (size_t)NB * NBLK2 * 4;// EE int2 (25.6 MB)
    constexpr size_t OFF_CSR  = OFF_EBUF + (size_t)EE * 8;      // EE ints (12.8 MB)
    constexpr size_t OFF_A8   = OFF_CSR + (size_t)EE * 4;       // NN*D fp8 (12.8 MB)
    constexpr size_t OFF_B8   = OFF_A8 + (size_t)NN * D;        // NN*D fp8
    int*    bintot = (int*)(ws + OFF_BT);
    int*    coff   = (int*)(ws + OFF_CO);
    float*  colsum = (float*)(ws + OFF_CS);
    char*   Wt1    = ws + OFF_WT1;
    char*   Wt2    = ws + OFF_WT2;
    int*    rowptr = (int*)(ws + OFF_RP);
    float*  norm   = (float*)(ws + OFF_NORM);
    int*    bh     = (int*)(ws + OFF_BH);
    int2*   ebuf   = (int2*)(ws + OFF_EBUF);
    int*    csr    = (int*)(ws + OFF_CSR);
    char*   bufA8  = ws + OFF_A8;
    char*   bufB8  = ws + OFF_B8;

    const int nT = 256;
    const int gridC = (NN * 32 + nT - 1) / nT;
    const int gridG = NN / 4;   // one wave per node, 4 waves/block

    // ---- CSR build + norm (no global atomics) ----
    block_hist<<<NBLK2, 256, 0, stream>>>(dst, bh);
    bin_scan<<<NB, 256, 0, stream>>>(bh, bintot);
    tiny_scan<<<1, 512, 0, stream>>>(bintot, coff);
    scatter2<<<NBLK2, 256, 0, stream>>>(src, dst, bh, coff, ebuf);
    fine_sort<<<NB, 256, 0, stream>>>((const long long*)ebuf, coff, rowptr, norm, csr);

    // ---- weight prep (fp8, transposed, x16) ----
    conv_w_fp8<<<32, 256, 0, stream>>>(W1, Wt1);
    conv_w_fp8<<<32, 256, 0, stream>>>(W2, Wt2);

    // ---- propagation block 1 (fp8 rows, cumulative x6 per round) ----
    convert_scale_fp8<<<gridC, nT, 0, stream>>>((const float4*)x, (int*)bufA8, norm);
    gather_fp8<0><<<gridG, 256, 0, stream>>>(rowptr, csr, bufA8, norm, bufB8, SCALE_R);
    gather_fp8<0><<<gridG, 256, 0, stream>>>(rowptr, csr, bufB8, norm, bufA8, SCALE_R);
    gather_fp8<1><<<gridG, 256, 0, stream>>>(rowptr, csr, bufA8, norm, bufB8, SCALE_R);
    // bufB8 = h * 216 (fp8)

    // ---- g = fp8(relu(h @ W1 + b1) * norm * SCALE_G) : B -> A (fp8 MFMA) ----
    gemm1_mfma<<<625, 256, 0, stream>>>(bufB8, Wt1, b1, norm, bufA8);

    // ---- propagation block 2 ----
    gather_fp8<0><<<gridG, 256, 0, stream>>>(rowptr, csr, bufA8, norm, bufB8, SCALE_R);
    gather_fp8<0><<<gridG, 256, 0, stream>>>(rowptr, csr, bufB8, norm, bufA8, SCALE_R);
    gather_fp8<1><<<gridG, 256, 0, stream>>>(rowptr, csr, bufA8, norm, bufB8, SCALE_R);
    // bufB8 = h2 * 512 * 216 (fp8)

    // ---- colsum of relu(h2 @ W2 + b2) (fp8 MFMA) ----
    hipMemsetAsync(colsum, 0, D * 4, stream);
    gemm2_mfma_colsum<<<250, 256, 0, stream>>>(bufB8, Wt2, b2, colsum);

    // ---- final MLP + sigmoid ----
    final_mlp<<<1, 128, 0, stream>>>(colsum, Wf1, bf1, Wf2, bf2, out);
}